// Round 5
// baseline (2249.839 us; speedup 1.0000x reference)
//
#include <hip/hip_runtime.h>

#define B_  256
#define N_  196
#define D_  2048
#define F_  512
#define ROWS (B_*N_)   // 50176
#define CAND 8

typedef _Float16 f16x8 __attribute__((ext_vector_type(8)));
typedef _Float16 f16x4 __attribute__((ext_vector_type(4)));
typedef float    f32x4 __attribute__((ext_vector_type(4)));

static __device__ __forceinline__ float wave_reduce_sum(float v) {
#pragma unroll
  for (int off = 32; off > 0; off >>= 1) v += __shfl_xor(v, off);
  return v;
}

// ---------- W [K][F] fp32  ->  Wt [F][K] fp16 ----------
__global__ __launch_bounds__(256) void wtrans_kernel(const float* __restrict__ W,
                                                     _Float16* __restrict__ Wt) {
  __shared__ float T[64][68];
  int k0 = blockIdx.x * 64;
  int f0 = blockIdx.y * 64;
  int tid = threadIdx.x;
  int c = tid & 63;
  int r4 = tid >> 6;
#pragma unroll
  for (int p = 0; p < 16; ++p) {
    int r = p * 4 + r4;
    T[r][c] = W[(size_t)(k0 + r) * F_ + f0 + c];
  }
  __syncthreads();
#pragma unroll
  for (int p = 0; p < 16; ++p) {
    int fr = p * 4 + r4;
    Wt[(size_t)(f0 + fr) * D_ + k0 + c] = (_Float16)T[c][fr];
  }
}

// ---------- sq[row] = numpy-pairwise fp32 sum of x*x (bit-faithful replica) ----------
// numpy pairwise_sum: leaves of 128 elems with 8 scalar accumulators
// (init r[q]=a[q], then 15 stride-8 adds), leaf combine
// ((r0+r1)+(r2+r3))+((r4+r5)+(r6+r7)), then exact binary tree over 16 leaves.
__global__ __launch_bounds__(256) void sq_np_kernel(const float* __restrict__ X,
                                                    float* __restrict__ sq) {
  __shared__ float C[4][128];
  int wave = threadIdx.x >> 6, lane = threadIdx.x & 63;
  int row = blockIdx.x * 4 + wave;
  const float* x = X + (size_t)row * D_;
#pragma unroll
  for (int s = 0; s < 2; ++s) {
    int h = lane + s * 64;            // chain id: leaf L=h>>3, accumulator q=h&7
    int base = (h >> 3) * 128 + (h & 7);
    float t0 = x[base];
    float r = __fmul_rn(t0, t0);
#pragma unroll
    for (int i = 1; i < 16; ++i) {
      float t = x[base + 8 * i];
      r = __fadd_rn(r, __fmul_rn(t, t));
    }
    C[wave][h] = r;
  }
  // same-wave LDS produce->consume (in-order within wave)
  if (lane == 0) {
    float leaf[16];
#pragma unroll
    for (int L = 0; L < 16; ++L) {
      const float* r = &C[wave][L * 8];
      leaf[L] = __fadd_rn(__fadd_rn(__fadd_rn(r[0], r[1]), __fadd_rn(r[2], r[3])),
                          __fadd_rn(__fadd_rn(r[4], r[5]), __fadd_rn(r[6], r[7])));
    }
    float b8[8];
#pragma unroll
    for (int t = 0; t < 8; ++t) b8[t] = __fadd_rn(leaf[2 * t], leaf[2 * t + 1]);
    float c4[4];
#pragma unroll
    for (int t = 0; t < 4; ++t) c4[t] = __fadd_rn(b8[2 * t], b8[2 * t + 1]);
    sq[row] = __fadd_rn(__fadd_rn(c4[0], c4[1]), __fadd_rn(c4[2], c4[3]));
  }
}

// ---------- H = X * W  (fp16 MFMA, fp32 accum). BM=64, BN=512(all of F), 512 thr ----------
__global__ __launch_bounds__(512, 2) void h_gemm(const float* __restrict__ X,
                                                 const _Float16* __restrict__ Wt,
                                                 float* __restrict__ H) {
  __shared__ _Float16 Al[64][40];
  __shared__ _Float16 Bl[512][40];
  int mBase = blockIdx.x * 64;
  int tid  = threadIdx.x;
  int lane = tid & 63;
  int wave = tid >> 6;
  int wr = wave >> 2;   // 0..1  (32 rows each)
  int wc = wave & 3;    // 0..3  (128 cols each)
  int fr_row = lane & 15;
  int fr_k   = (lane >> 4) * 8;
  f32x4 acc[2][8] = {};
  int arow = tid >> 3;         // 0..63
  int akk  = (tid & 7) * 4;
  for (int k0 = 0; k0 < D_; k0 += 32) {
    float4 av = *(const float4*)&X[(size_t)(mBase + arow) * D_ + k0 + akk];
    f16x4 ah = { (_Float16)av.x, (_Float16)av.y, (_Float16)av.z, (_Float16)av.w };
    f16x8 b0 = *(const f16x8*)&Wt[(size_t)tid * D_ + k0 + 0];
    f16x8 b1 = *(const f16x8*)&Wt[(size_t)tid * D_ + k0 + 8];
    f16x8 b2 = *(const f16x8*)&Wt[(size_t)tid * D_ + k0 + 16];
    f16x8 b3 = *(const f16x8*)&Wt[(size_t)tid * D_ + k0 + 24];
    *(f16x4*)&Al[arow][akk] = ah;
    *(f16x8*)&Bl[tid][0]  = b0;
    *(f16x8*)&Bl[tid][8]  = b1;
    *(f16x8*)&Bl[tid][16] = b2;
    *(f16x8*)&Bl[tid][24] = b3;
    __syncthreads();
    f16x8 af[2], bf[8];
#pragma unroll
    for (int m = 0; m < 2; ++m) af[m] = *(const f16x8*)&Al[wr * 32 + m * 16 + fr_row][fr_k];
#pragma unroll
    for (int n = 0; n < 8; ++n) bf[n] = *(const f16x8*)&Bl[wc * 128 + n * 16 + fr_row][fr_k];
#pragma unroll
    for (int m = 0; m < 2; ++m)
#pragma unroll
      for (int n = 0; n < 8; ++n)
        acc[m][n] = __builtin_amdgcn_mfma_f32_16x16x32_f16(af[m], bf[n], acc[m][n], 0, 0, 0);
    __syncthreads();
  }
  // C/D layout: row = (lane>>4)*4 + i, col = lane&15  [verified mapping]
  int orow0 = mBase + wr * 32 + (lane >> 4) * 4;
#pragma unroll
  for (int m = 0; m < 2; ++m) {
#pragma unroll
    for (int n = 0; n < 8; ++n) {
      int col = wc * 128 + n * 16 + (lane & 15);
#pragma unroll
      for (int i = 0; i < 4; ++i)
        H[(size_t)(orow0 + m * 16 + i) * F_ + col] = acc[m][n][i];
    }
  }
}

// ---------- e_src/e_dst = H . a_src / a_dst ----------
__global__ __launch_bounds__(256) void e_kernel(const float* __restrict__ H,
                                                const float* __restrict__ as,
                                                const float* __restrict__ ad,
                                                float* __restrict__ es,
                                                float* __restrict__ ed) {
  int row  = blockIdx.x * 4 + (threadIdx.x >> 6);
  int lane = threadIdx.x & 63;
  const float* h = H + (size_t)row * F_;
  float s = 0.f, d = 0.f;
#pragma unroll
  for (int p = 0; p < 2; ++p) {
    int col = p * 256 + lane * 4;
    float4 hv = *(const float4*)&h[col];
    float4 av = *(const float4*)&as[col];
    float4 dv = *(const float4*)&ad[col];
    s += hv.x * av.x + hv.y * av.y + hv.z * av.z + hv.w * av.w;
    d += hv.x * dv.x + hv.y * dv.y + hv.z * dv.z + hv.w * dv.w;
  }
  s = wave_reduce_sum(s);
  d = wave_reduce_sum(d);
  if (lane == 0) { es[row] = s; ed[row] = d; }
}

// ---------- kNN: fp16-MFMA screen (top-8) -> numpy-fp32-replica d2 -> top-5 + softmax ----------
__global__ __launch_bounds__(256, 2) void knn_kernel(const float* __restrict__ X,
                                                     const float* __restrict__ sq,
                                                     const float* __restrict__ es,
                                                     const float* __restrict__ ed,
                                                     int* __restrict__ idx5,
                                                     float* __restrict__ alpha5) {
  __shared__ _Float16 T[256][40];   // all points of this batch (padded), fp16
  __shared__ float    S[64][212];   // screened scores for this block's 64 i-rows
  int b  = blockIdx.y;
  int i0 = blockIdx.x * 64;
  int tid  = threadIdx.x;
  int lane = tid & 63;
  int wave = tid >> 6;
  const float* Xb  = X  + (size_t)b * N_ * D_;
  const float* sqb = sq + (size_t)b * N_;
  int fr_row = lane & 15;
  int fr_k   = (lane >> 4) * 8;
  f32x4 acc[13] = {};
  int srow = tid >> 3;        // 0..31
  int skk  = (tid & 7) * 4;
  for (int k0 = 0; k0 < D_; k0 += 32) {
#pragma unroll
    for (int p = 0; p < 8; ++p) {
      int r = p * 32 + srow;
      float4 v = make_float4(0.f, 0.f, 0.f, 0.f);
      if (r < N_) v = *(const float4*)&Xb[(size_t)r * D_ + k0 + skk];
      f16x4 hv = { (_Float16)v.x, (_Float16)v.y, (_Float16)v.z, (_Float16)v.w };
      *(f16x4*)&T[r][skk] = hv;
    }
    __syncthreads();
    f16x8 a = *(const f16x8*)&T[i0 + wave * 16 + fr_row][fr_k];
#pragma unroll
    for (int n = 0; n < 13; ++n) {
      f16x8 bfr = *(const f16x8*)&T[n * 16 + fr_row][fr_k];
      acc[n] = __builtin_amdgcn_mfma_f32_16x16x32_f16(a, bfr, acc[n], 0, 0, 0);
    }
    __syncthreads();
  }
  // screen scores: s_j = sq[j] - 2*G[i][j]   (same ordering as d2; tolerance ~300 sigma)
  int il = wave * 16 + (lane >> 4) * 4;
#pragma unroll
  for (int n = 0; n < 13; ++n) {
    int j = n * 16 + (lane & 15);
#pragma unroll
    for (int i = 0; i < 4; ++i) {
      float s = 1e30f;
      if (j < N_) s = sqb[j] - 2.0f * acc[n][i];
      S[il + i][j] = s;
    }
  }
  __syncthreads();
  // each wave consumes only rows it wrote
  for (int rr = 0; rr < 16; ++rr) {
    int ig = i0 + wave * 16 + rr;
    if (ig >= N_) break;                  // wave-uniform
    const int r_glob = b * N_ + ig;
    float v0 = S[wave * 16 + rr][lane];
    float v1 = S[wave * 16 + rr][lane + 64];
    float v2 = S[wave * 16 + rr][lane + 128];
    float v3 = (lane < 16) ? S[wave * 16 + rr][lane + 192] : 1e30f;
    int cand[CAND];
#pragma unroll
    for (int it = 0; it < CAND; ++it) {
      float m = v0; int js = lane;
      if (v1 < m) { m = v1; js = lane + 64; }
      if (v2 < m) { m = v2; js = lane + 128; }
      if (v3 < m) { m = v3; js = lane + 192; }
#pragma unroll
      for (int off = 32; off > 0; off >>= 1) {
        float om = __shfl_xor(m, off);
        int   oj = __shfl_xor(js, off);
        if (om < m || (om == m && oj < js)) { m = om; js = oj; }
      }
      cand[it] = js;
      if (js == lane)            v0 = 1e30f;
      else if (js == lane + 64)  v1 = 1e30f;
      else if (js == lane + 128) v2 = 1e30f;
      else if (js == lane + 192) v3 = 1e30f;
    }
    // ---- numpy-fp32-replica d2 for the 8 candidates ----
    // G replicates np.einsum contig_two (baseline SSE): one 4-lane vector
    // accumulator, chained muladd (separate fp32 mul+add, no FMA), lane l
    // sums d == l (mod 4) in increasing d; hsum = (s0+s1)+(s2+s3) (SSE hadd,
    // bitwise == numpy's shuffle sequence by commutativity).
    // d2 = fl32( fl32(sq_i + sq_j) - 2*G )
    const float* xi = Xb + (size_t)ig * D_;
    float sqi = sqb[ig];
    float sqv[CAND];
#pragma unroll
    for (int c = 0; c < CAND; ++c) sqv[c] = sqb[cand[c]];
    int grp8 = (lane >> 2) & 7;   // candidate computed by this 4-lane group
    int l4 = lane & 3;
    const float* xj = Xb + (size_t)cand[grp8] * D_;
    float aacc = 0.f;
    for (int s5 = 0; s5 < 512; ++s5) {
      int d = s5 * 4 + l4;
      aacc = __fadd_rn(aacc, __fmul_rn(xi[d], xj[d]));
    }
    float d2c[CAND];
#pragma unroll
    for (int c = 0; c < CAND; ++c) {
      float s0 = __shfl(aacc, c * 4 + 0);
      float s1 = __shfl(aacc, c * 4 + 1);
      float s2 = __shfl(aacc, c * 4 + 2);
      float s3 = __shfl(aacc, c * 4 + 3);
      float G  = __fadd_rn(__fadd_rn(s0, s1), __fadd_rn(s2, s3));
      float Sij = __fadd_rn(sqi, sqv[c]);
      d2c[c] = __fsub_rn(Sij, __fadd_rn(G, G));
    }
    // rank-based top-5 on replica fp32 scores; ties -> smaller neighbor index (jax top_k)
    int rnk[CAND];
#pragma unroll
    for (int c = 0; c < CAND; ++c) {
      int r = 0;
#pragma unroll
      for (int c2 = 0; c2 < CAND; ++c2)
        if (c2 != c && (d2c[c2] < d2c[c] || (d2c[c2] == d2c[c] && cand[c2] < cand[c]))) r++;
      rnk[c] = r;
    }
    int ordj[5];
#pragma unroll
    for (int m5 = 0; m5 < 5; ++m5) {
      int oj = 0;
#pragma unroll
      for (int c = 0; c < CAND; ++c)
        if (rnk[c] == m5) oj = cand[c];
      ordj[m5] = oj;
    }
    // alphas: softmax over leaky_relu(e_src[i]+e_dst[j]) of the 5 neighbors
    float ei = es[r_glob];
    float ev[5];
#pragma unroll
    for (int m5 = 0; m5 < 5; ++m5) {
      float e = ei + ed[b * N_ + ordj[m5]];
      ev[m5] = e > 0.f ? e : 0.2f * e;
    }
    float mx = fmaxf(fmaxf(fmaxf(ev[0], ev[1]), fmaxf(ev[2], ev[3])), ev[4]);
    float p0 = expf(ev[0] - mx), p1 = expf(ev[1] - mx), p2 = expf(ev[2] - mx),
          p3 = expf(ev[3] - mx), p4 = expf(ev[4] - mx);
    float inv = 1.0f / (p0 + p1 + p2 + p3 + p4);
    if (lane == 0) {
      size_t o = (size_t)r_glob * 5;
      idx5[o + 0] = ordj[0]; alpha5[o + 0] = p0 * inv;
      idx5[o + 1] = ordj[1]; alpha5[o + 1] = p1 * inv;
      idx5[o + 2] = ordj[2]; alpha5[o + 2] = p2 * inv;
      idx5[o + 3] = ordj[3]; alpha5[o + 3] = p3 * inv;
      idx5[o + 4] = ordj[4]; alpha5[o + 4] = p4 * inv;
    }
  }
}

// ---------- out[b,i,:] = elu( sum_c alpha_c * H[b, j_c, :] ) ----------
__global__ __launch_bounds__(128) void agg_kernel(const float* __restrict__ H,
                                                  const int* __restrict__ idx5,
                                                  const float* __restrict__ alpha5,
                                                  float* __restrict__ out) {
  int row = blockIdx.x;
  int b = row / N_;
  int t = threadIdx.x;
  size_t base5 = (size_t)row * 5;
  const float* Hb = H + (size_t)b * N_ * F_;
  float ax = 0.f, ay = 0.f, az = 0.f, aw = 0.f;
#pragma unroll
  for (int c = 0; c < 5; ++c) {
    int j   = idx5[base5 + c];
    float a = alpha5[base5 + c];
    float4 hv = *(const float4*)&Hb[(size_t)j * F_ + t * 4];
    ax += a * hv.x; ay += a * hv.y; az += a * hv.z; aw += a * hv.w;
  }
  float4 o;
  o.x = ax > 0.f ? ax : expf(ax) - 1.f;
  o.y = ay > 0.f ? ay : expf(ay) - 1.f;
  o.z = az > 0.f ? az : expf(az) - 1.f;
  o.w = aw > 0.f ? aw : expf(aw) - 1.f;
  *(float4*)&out[(size_t)row * F_ + t * 4] = o;
}

extern "C" void kernel_launch(void* const* d_in, const int* in_sizes, int n_in,
                              void* d_out, int out_size, void* d_ws, size_t ws_size,
                              hipStream_t stream) {
  const float* X    = (const float*)d_in[0];
  const float* W    = (const float*)d_in[1];
  const float* Asrc = (const float*)d_in[2];
  const float* Adst = (const float*)d_in[3];
  float* out = (float*)d_out;

  // workspace layout (bytes)
  const size_t OFF_WT   = 0;                          // 512*2048*2      = 2,097,152
  const size_t OFF_SQ   = 2097152;                    // 50176*4         =   200,704
  const size_t OFF_ES   = OFF_SQ + 200704;
  const size_t OFF_ED   = OFF_ES + 200704;
  const size_t OFF_IDX  = OFF_ED + 200704;            // 50176*5*4
  const size_t OFF_ALP  = OFF_IDX + 1003520;
  const size_t OFF_H    = OFF_ALP + 1003520;          // 50176*512*4 = 102,760,448
  const size_t NEEDED   = OFF_H + (size_t)ROWS * F_ * 4;
  if (ws_size < NEEDED) return;  // diagnostic: bench will fail with poison -> ws too small

  char* ws = (char*)d_ws;
  _Float16* Wt = (_Float16*)(ws + OFF_WT);
  float* sq     = (float*)(ws + OFF_SQ);
  float* es     = (float*)(ws + OFF_ES);
  float* ed     = (float*)(ws + OFF_ED);
  int*   idx5   = (int*)  (ws + OFF_IDX);
  float* alpha5 = (float*)(ws + OFF_ALP);
  float* H      = (float*)(ws + OFF_H);

  wtrans_kernel<<<dim3(32, 8), 256, 0, stream>>>(W, Wt);
  sq_np_kernel<<<ROWS / 4, 256, 0, stream>>>(X, sq);
  h_gemm<<<ROWS / 64, 512, 0, stream>>>(X, Wt, H);
  e_kernel<<<ROWS / 4, 256, 0, stream>>>(H, Asrc, Adst, es, ed);
  knn_kernel<<<dim3(4, B_), 256, 0, stream>>>(X, sq, es, ed, idx5, alpha5);
  agg_kernel<<<ROWS, 128, 0, stream>>>(H, idx5, alpha5, out);
}

// Round 6
// 1229.954 us; speedup vs baseline: 1.8292x; 1.8292x over previous
//
#include <hip/hip_runtime.h>

#define B_  256
#define N_  196
#define D_  2048
#define F_  512
#define ROWS (B_*N_)   // 50176
#define CAND 8

typedef _Float16 f16x8 __attribute__((ext_vector_type(8)));
typedef _Float16 f16x4 __attribute__((ext_vector_type(4)));
typedef float    f32x4 __attribute__((ext_vector_type(4)));

static __device__ __forceinline__ float wave_reduce_sum(float v) {
#pragma unroll
  for (int off = 32; off > 0; off >>= 1) v += __shfl_xor(v, off);
  return v;
}

static __device__ __forceinline__ double wave_reduce_sum_d(double v) {
#pragma unroll
  for (int off = 32; off > 0; off >>= 1) v += __shfl_xor(v, off);
  return v;
}

// ---------- W [K][F] fp32  ->  Wt [F][K] fp16 ----------
__global__ __launch_bounds__(256) void wtrans_kernel(const float* __restrict__ W,
                                                     _Float16* __restrict__ Wt) {
  __shared__ float T[64][68];
  int k0 = blockIdx.x * 64;
  int f0 = blockIdx.y * 64;
  int tid = threadIdx.x;
  int c = tid & 63;
  int r4 = tid >> 6;
#pragma unroll
  for (int p = 0; p < 16; ++p) {
    int r = p * 4 + r4;
    T[r][c] = W[(size_t)(k0 + r) * F_ + f0 + c];
  }
  __syncthreads();
#pragma unroll
  for (int p = 0; p < 16; ++p) {
    int fr = p * 4 + r4;
    Wt[(size_t)(f0 + fr) * D_ + k0 + c] = (_Float16)T[c][fr];
  }
}

// ---------- sq[row] = numpy-pairwise fp32 sum of x*x (bit-faithful replica) ----------
__global__ __launch_bounds__(256) void sq_np_kernel(const float* __restrict__ X,
                                                    float* __restrict__ sq) {
  __shared__ float C[4][128];
  int wave = threadIdx.x >> 6, lane = threadIdx.x & 63;
  int row = blockIdx.x * 4 + wave;
  const float* x = X + (size_t)row * D_;
#pragma unroll
  for (int s = 0; s < 2; ++s) {
    int h = lane + s * 64;            // chain id: leaf L=h>>3, accumulator q=h&7
    int base = (h >> 3) * 128 + (h & 7);
    float t0 = x[base];
    float r = __fmul_rn(t0, t0);
#pragma unroll
    for (int i = 1; i < 16; ++i) {
      float t = x[base + 8 * i];
      r = __fadd_rn(r, __fmul_rn(t, t));
    }
    C[wave][h] = r;
  }
  if (lane == 0) {
    float leaf[16];
#pragma unroll
    for (int L = 0; L < 16; ++L) {
      const float* r = &C[wave][L * 8];
      leaf[L] = __fadd_rn(__fadd_rn(__fadd_rn(r[0], r[1]), __fadd_rn(r[2], r[3])),
                          __fadd_rn(__fadd_rn(r[4], r[5]), __fadd_rn(r[6], r[7])));
    }
    float b8[8];
#pragma unroll
    for (int t = 0; t < 8; ++t) b8[t] = __fadd_rn(leaf[2 * t], leaf[2 * t + 1]);
    float c4[4];
#pragma unroll
    for (int t = 0; t < 4; ++t) c4[t] = __fadd_rn(b8[2 * t], b8[2 * t + 1]);
    sq[row] = __fadd_rn(__fadd_rn(c4[0], c4[1]), __fadd_rn(c4[2], c4[3]));
  }
}

// ---------- H = X * W  (fp16 MFMA, fp32 accum). BM=64, BN=512(all of F), 512 thr ----------
__global__ __launch_bounds__(512, 2) void h_gemm(const float* __restrict__ X,
                                                 const _Float16* __restrict__ Wt,
                                                 float* __restrict__ H) {
  __shared__ _Float16 Al[64][40];
  __shared__ _Float16 Bl[512][40];
  int mBase = blockIdx.x * 64;
  int tid  = threadIdx.x;
  int lane = tid & 63;
  int wave = tid >> 6;
  int wr = wave >> 2;   // 0..1  (32 rows each)
  int wc = wave & 3;    // 0..3  (128 cols each)
  int fr_row = lane & 15;
  int fr_k   = (lane >> 4) * 8;
  f32x4 acc[2][8] = {};
  int arow = tid >> 3;         // 0..63
  int akk  = (tid & 7) * 4;
  for (int k0 = 0; k0 < D_; k0 += 32) {
    float4 av = *(const float4*)&X[(size_t)(mBase + arow) * D_ + k0 + akk];
    f16x4 ah = { (_Float16)av.x, (_Float16)av.y, (_Float16)av.z, (_Float16)av.w };
    f16x8 b0 = *(const f16x8*)&Wt[(size_t)tid * D_ + k0 + 0];
    f16x8 b1 = *(const f16x8*)&Wt[(size_t)tid * D_ + k0 + 8];
    f16x8 b2 = *(const f16x8*)&Wt[(size_t)tid * D_ + k0 + 16];
    f16x8 b3 = *(const f16x8*)&Wt[(size_t)tid * D_ + k0 + 24];
    *(f16x4*)&Al[arow][akk] = ah;
    *(f16x8*)&Bl[tid][0]  = b0;
    *(f16x8*)&Bl[tid][8]  = b1;
    *(f16x8*)&Bl[tid][16] = b2;
    *(f16x8*)&Bl[tid][24] = b3;
    __syncthreads();
    f16x8 af[2], bf[8];
#pragma unroll
    for (int m = 0; m < 2; ++m) af[m] = *(const f16x8*)&Al[wr * 32 + m * 16 + fr_row][fr_k];
#pragma unroll
    for (int n = 0; n < 8; ++n) bf[n] = *(const f16x8*)&Bl[wc * 128 + n * 16 + fr_row][fr_k];
#pragma unroll
    for (int m = 0; m < 2; ++m)
#pragma unroll
      for (int n = 0; n < 8; ++n)
        acc[m][n] = __builtin_amdgcn_mfma_f32_16x16x32_f16(af[m], bf[n], acc[m][n], 0, 0, 0);
    __syncthreads();
  }
  int orow0 = mBase + wr * 32 + (lane >> 4) * 4;
#pragma unroll
  for (int m = 0; m < 2; ++m) {
#pragma unroll
    for (int n = 0; n < 8; ++n) {
      int col = wc * 128 + n * 16 + (lane & 15);
#pragma unroll
      for (int i = 0; i < 4; ++i)
        H[(size_t)(orow0 + m * 16 + i) * F_ + col] = acc[m][n][i];
    }
  }
}

// ---------- e_src/e_dst = H . a_src / a_dst ----------
__global__ __launch_bounds__(256) void e_kernel(const float* __restrict__ H,
                                                const float* __restrict__ as,
                                                const float* __restrict__ ad,
                                                float* __restrict__ es,
                                                float* __restrict__ ed) {
  int row  = blockIdx.x * 4 + (threadIdx.x >> 6);
  int lane = threadIdx.x & 63;
  const float* h = H + (size_t)row * F_;
  float s = 0.f, d = 0.f;
#pragma unroll
  for (int p = 0; p < 2; ++p) {
    int col = p * 256 + lane * 4;
    float4 hv = *(const float4*)&h[col];
    float4 av = *(const float4*)&as[col];
    float4 dv = *(const float4*)&ad[col];
    s += hv.x * av.x + hv.y * av.y + hv.z * av.z + hv.w * av.w;
    d += hv.x * dv.x + hv.y * dv.y + hv.z * dv.z + hv.w * dv.w;
  }
  s = wave_reduce_sum(s);
  d = wave_reduce_sum(d);
  if (lane == 0) { es[row] = s; ed[row] = d; }
}

// ---------- kNN: fp16-MFMA screen -> 3-tier gated recheck -> top-5 set + softmax ----------
// Tier1 (screen gap > 0.75, ~92%): accept screen top-5 set (12-sigma safe).
// Tier2 (fp64 coalesced recheck, ~8%): accept if fp64 gap > 4e-3 (> 2x max ref fp32 err).
// Tier3 (bit-exact numpy replica, ~20 rows total): decides true ties.
__global__ __launch_bounds__(256, 2) void knn_kernel(const float* __restrict__ X,
                                                     const float* __restrict__ sq,
                                                     const float* __restrict__ es,
                                                     const float* __restrict__ ed,
                                                     int* __restrict__ idx5,
                                                     float* __restrict__ alpha5) {
  __shared__ _Float16 T[256][40];   // all points of this batch (padded), fp16
  __shared__ float    S[64][212];   // screened scores for this block's 64 i-rows
  int b  = blockIdx.y;
  int i0 = blockIdx.x * 64;
  int tid  = threadIdx.x;
  int lane = tid & 63;
  int wave = tid >> 6;
  const float* Xb  = X  + (size_t)b * N_ * D_;
  const float* sqb = sq + (size_t)b * N_;
  int fr_row = lane & 15;
  int fr_k   = (lane >> 4) * 8;
  f32x4 acc[13] = {};
  int srow = tid >> 3;        // 0..31
  int skk  = (tid & 7) * 4;
  for (int k0 = 0; k0 < D_; k0 += 32) {
#pragma unroll
    for (int p = 0; p < 8; ++p) {
      int r = p * 32 + srow;
      float4 v = make_float4(0.f, 0.f, 0.f, 0.f);
      if (r < N_) v = *(const float4*)&Xb[(size_t)r * D_ + k0 + skk];
      f16x4 hv = { (_Float16)v.x, (_Float16)v.y, (_Float16)v.z, (_Float16)v.w };
      *(f16x4*)&T[r][skk] = hv;
    }
    __syncthreads();
    f16x8 a = *(const f16x8*)&T[i0 + wave * 16 + fr_row][fr_k];
#pragma unroll
    for (int n = 0; n < 13; ++n) {
      f16x8 bfr = *(const f16x8*)&T[n * 16 + fr_row][fr_k];
      acc[n] = __builtin_amdgcn_mfma_f32_16x16x32_f16(a, bfr, acc[n], 0, 0, 0);
    }
    __syncthreads();
  }
  // screen scores: s_j = sq[j] - 2*G[i][j]
  int il = wave * 16 + (lane >> 4) * 4;
#pragma unroll
  for (int n = 0; n < 13; ++n) {
    int j = n * 16 + (lane & 15);
#pragma unroll
    for (int i = 0; i < 4; ++i) {
      float s = 1e30f;
      if (j < N_) s = sqb[j] - 2.0f * acc[n][i];
      S[il + i][j] = s;
    }
  }
  __syncthreads();
  // each wave consumes only rows it wrote
  for (int rr = 0; rr < 16; ++rr) {
    int ig = i0 + wave * 16 + rr;
    if (ig >= N_) break;                  // wave-uniform
    const int r_glob = b * N_ + ig;
    float v0 = S[wave * 16 + rr][lane];
    float v1 = S[wave * 16 + rr][lane + 64];
    float v2 = S[wave * 16 + rr][lane + 128];
    float v3 = (lane < 16) ? S[wave * 16 + rr][lane + 192] : 1e30f;
    int cand[CAND];
    float msc[CAND];
#pragma unroll
    for (int it = 0; it < CAND; ++it) {
      float m = v0; int js = lane;
      if (v1 < m) { m = v1; js = lane + 64; }
      if (v2 < m) { m = v2; js = lane + 128; }
      if (v3 < m) { m = v3; js = lane + 192; }
#pragma unroll
      for (int off = 32; off > 0; off >>= 1) {
        float om = __shfl_xor(m, off);
        int   oj = __shfl_xor(js, off);
        if (om < m || (om == m && oj < js)) { m = om; js = oj; }
      }
      cand[it] = js;
      msc[it] = m;
      if (js == lane)            v0 = 1e30f;
      else if (js == lane + 64)  v1 = 1e30f;
      else if (js == lane + 128) v2 = 1e30f;
      else if (js == lane + 192) v3 = 1e30f;
    }
    int ordj[5];
    // ---- Tier 1: screen-gap gate (wave-uniform values) ----
    if (msc[5] - msc[4] > 0.75f) {
#pragma unroll
      for (int m5 = 0; m5 < 5; ++m5) ordj[m5] = cand[m5];
    } else {
      // ---- Tier 2: fp64 coalesced recheck of the 8 candidates ----
      const float* xi = Xb + (size_t)ig * D_;
      float4 xr[8];
#pragma unroll
      for (int q = 0; q < 8; ++q) xr[q] = *(const float4*)&xi[q * 256 + lane * 4];
      double s8[CAND];
#pragma unroll
      for (int c = 0; c < CAND; ++c) {
        const float* xj = Xb + (size_t)cand[c] * D_;
        double dsum = 0.0, sqc = 0.0;
#pragma unroll
        for (int q = 0; q < 8; ++q) {
          float4 u = *(const float4*)&xj[q * 256 + lane * 4];
          dsum += (double)xr[q].x * (double)u.x + (double)xr[q].y * (double)u.y
                + (double)xr[q].z * (double)u.z + (double)xr[q].w * (double)u.w;
          sqc  += (double)u.x * (double)u.x + (double)u.y * (double)u.y
                + (double)u.z * (double)u.z + (double)u.w * (double)u.w;
        }
        dsum = wave_reduce_sum_d(dsum);
        sqc  = wave_reduce_sum_d(sqc);
        s8[c] = sqc - 2.0 * dsum;
      }
      int rnk[CAND];
#pragma unroll
      for (int c = 0; c < CAND; ++c) {
        int r = 0;
#pragma unroll
        for (int c2 = 0; c2 < CAND; ++c2)
          if (c2 != c && (s8[c2] < s8[c] || (s8[c2] == s8[c] && cand[c2] < cand[c]))) r++;
        rnk[c] = r;
      }
      double g5 = 0.0, g6 = 0.0;
#pragma unroll
      for (int c = 0; c < CAND; ++c) {
        if (rnk[c] == 4) g5 = s8[c];
        if (rnk[c] == 5) g6 = s8[c];
      }
#pragma unroll
      for (int m5 = 0; m5 < 5; ++m5) {
        int oj = 0;
#pragma unroll
        for (int c = 0; c < CAND; ++c)
          if (rnk[c] == m5) oj = cand[c];
        ordj[m5] = oj;
      }
      // ---- Tier 3: bit-exact numpy replica (rare true near-ties) ----
      if (!(g6 - g5 > 4e-3)) {
        float sqi = sqb[ig];
        float sqv[CAND];
#pragma unroll
        for (int c = 0; c < CAND; ++c) sqv[c] = sqb[cand[c]];
        int grp8 = (lane >> 2) & 7;
        int l4 = lane & 3;
        const float* xjr = Xb + (size_t)cand[grp8] * D_;
        float aacc = 0.f;
        for (int s5 = 0; s5 < 512; ++s5) {
          int d = s5 * 4 + l4;
          aacc = __fadd_rn(aacc, __fmul_rn(xi[d], xjr[d]));
        }
        float d2c[CAND];
#pragma unroll
        for (int c = 0; c < CAND; ++c) {
          float s0 = __shfl(aacc, c * 4 + 0);
          float s1 = __shfl(aacc, c * 4 + 1);
          float s2 = __shfl(aacc, c * 4 + 2);
          float s3 = __shfl(aacc, c * 4 + 3);
          float G  = __fadd_rn(__fadd_rn(s0, s1), __fadd_rn(s2, s3));
          float Sij = __fadd_rn(sqi, sqv[c]);
          d2c[c] = __fsub_rn(Sij, __fadd_rn(G, G));
        }
        int rnk3[CAND];
#pragma unroll
        for (int c = 0; c < CAND; ++c) {
          int r = 0;
#pragma unroll
          for (int c2 = 0; c2 < CAND; ++c2)
            if (c2 != c && (d2c[c2] < d2c[c] || (d2c[c2] == d2c[c] && cand[c2] < cand[c]))) r++;
          rnk3[c] = r;
        }
#pragma unroll
        for (int m5 = 0; m5 < 5; ++m5) {
          int oj = 0;
#pragma unroll
          for (int c = 0; c < CAND; ++c)
            if (rnk3[c] == m5) oj = cand[c];
          ordj[m5] = oj;
        }
      }
    }
    // alphas: softmax over leaky_relu(e_src[i]+e_dst[j]) of the 5 neighbors
    float ei = es[r_glob];
    float ev[5];
#pragma unroll
    for (int m5 = 0; m5 < 5; ++m5) {
      float e = ei + ed[b * N_ + ordj[m5]];
      ev[m5] = e > 0.f ? e : 0.2f * e;
    }
    float mx = fmaxf(fmaxf(fmaxf(ev[0], ev[1]), fmaxf(ev[2], ev[3])), ev[4]);
    float p0 = expf(ev[0] - mx), p1 = expf(ev[1] - mx), p2 = expf(ev[2] - mx),
          p3 = expf(ev[3] - mx), p4 = expf(ev[4] - mx);
    float inv = 1.0f / (p0 + p1 + p2 + p3 + p4);
    if (lane == 0) {
      size_t o = (size_t)r_glob * 5;
      idx5[o + 0] = ordj[0]; alpha5[o + 0] = p0 * inv;
      idx5[o + 1] = ordj[1]; alpha5[o + 1] = p1 * inv;
      idx5[o + 2] = ordj[2]; alpha5[o + 2] = p2 * inv;
      idx5[o + 3] = ordj[3]; alpha5[o + 3] = p3 * inv;
      idx5[o + 4] = ordj[4]; alpha5[o + 4] = p4 * inv;
    }
  }
}

// ---------- out[b,i,:] = elu( sum_c alpha_c * H[b, j_c, :] ) ----------
__global__ __launch_bounds__(128) void agg_kernel(const float* __restrict__ H,
                                                  const int* __restrict__ idx5,
                                                  const float* __restrict__ alpha5,
                                                  float* __restrict__ out) {
  int row = blockIdx.x;
  int b = row / N_;
  int t = threadIdx.x;
  size_t base5 = (size_t)row * 5;
  const float* Hb = H + (size_t)b * N_ * F_;
  float ax = 0.f, ay = 0.f, az = 0.f, aw = 0.f;
#pragma unroll
  for (int c = 0; c < 5; ++c) {
    int j   = idx5[base5 + c];
    float a = alpha5[base5 + c];
    float4 hv = *(const float4*)&Hb[(size_t)j * F_ + t * 4];
    ax += a * hv.x; ay += a * hv.y; az += a * hv.z; aw += a * hv.w;
  }
  float4 o;
  o.x = ax > 0.f ? ax : expf(ax) - 1.f;
  o.y = ay > 0.f ? ay : expf(ay) - 1.f;
  o.z = az > 0.f ? az : expf(az) - 1.f;
  o.w = aw > 0.f ? aw : expf(aw) - 1.f;
  *(float4*)&out[(size_t)row * F_ + t * 4] = o;
}

extern "C" void kernel_launch(void* const* d_in, const int* in_sizes, int n_in,
                              void* d_out, int out_size, void* d_ws, size_t ws_size,
                              hipStream_t stream) {
  const float* X    = (const float*)d_in[0];
  const float* W    = (const float*)d_in[1];
  const float* Asrc = (const float*)d_in[2];
  const float* Adst = (const float*)d_in[3];
  float* out = (float*)d_out;

  const size_t OFF_WT   = 0;                          // 512*2048*2      = 2,097,152
  const size_t OFF_SQ   = 2097152;                    // 50176*4         =   200,704
  const size_t OFF_ES   = OFF_SQ + 200704;
  const size_t OFF_ED   = OFF_ES + 200704;
  const size_t OFF_IDX  = OFF_ED + 200704;            // 50176*5*4
  const size_t OFF_ALP  = OFF_IDX + 1003520;
  const size_t OFF_H    = OFF_ALP + 1003520;          // 50176*512*4 = 102,760,448
  const size_t NEEDED   = OFF_H + (size_t)ROWS * F_ * 4;
  if (ws_size < NEEDED) return;

  char* ws = (char*)d_ws;
  _Float16* Wt = (_Float16*)(ws + OFF_WT);
  float* sq     = (float*)(ws + OFF_SQ);
  float* es     = (float*)(ws + OFF_ES);
  float* ed     = (float*)(ws + OFF_ED);
  int*   idx5   = (int*)  (ws + OFF_IDX);
  float* alpha5 = (float*)(ws + OFF_ALP);
  float* H      = (float*)(ws + OFF_H);

  wtrans_kernel<<<dim3(32, 8), 256, 0, stream>>>(W, Wt);
  sq_np_kernel<<<ROWS / 4, 256, 0, stream>>>(X, sq);
  h_gemm<<<ROWS / 64, 512, 0, stream>>>(X, Wt, H);
  e_kernel<<<ROWS / 4, 256, 0, stream>>>(H, Asrc, Adst, es, ed);
  knn_kernel<<<dim3(4, B_), 256, 0, stream>>>(X, sq, es, ed, idx5, alpha5);
  agg_kernel<<<ROWS, 128, 0, stream>>>(H, idx5, alpha5, out);
}